// Round 3
// baseline (36.644 us; speedup 1.0000x reference)
//
#include <hip/hip_runtime.h>
#include <math.h>

#define BATCH 4096
#define KMAX 50
#define DIM 256
#define NITER 13   // ceil(50/4): wave w covers k = w + 4*i, clamped

__global__ __launch_bounds__(256) void kv_memory_kernel(
    const int* __restrict__ keys,          // B*K
    const int* __restrict__ values,        // B*K
    const int* __restrict__ pair_len,      // B
    const float* __restrict__ query,       // B*D
    const float* __restrict__ key_table,   // NUM_KEYS*D
    const float* __restrict__ value_table, // NUM_VALUES*D
    float* __restrict__ out)               // B*D
{
    const int b    = blockIdx.x;
    const int tid  = threadIdx.x;
    const int lane = tid & 63;
    const int wave = tid >> 6;

    __shared__ int    s_keys[KMAX];
    __shared__ int    s_vals[KMAX];
    __shared__ float  s_logit[64];
    __shared__ float4 s_acc[4][64];

    int len = pair_len[b];
    if (len < 1) len = 1;
    if (len > KMAX) len = KMAX;

    if (tid < KMAX) {
        s_keys[tid] = keys[b * KMAX + tid];
        s_vals[tid] = values[b * KMAX + tid];
    }

    // Each lane owns 4 consecutive dims: d0 = lane*4
    const float4 q = *reinterpret_cast<const float4*>(query + (size_t)b * DIM + lane * 4);
    __syncthreads();

    // ---- Compute all clamped gather indices up front ----
    int kidx[NITER], vidx[NITER];
    #pragma unroll
    for (int i = 0; i < NITER; ++i) {
        const int k  = wave + 4 * i;
        const int kc = (k < len) ? k : (len - 1);
        kidx[i] = s_keys[kc];
        vidx[i] = s_vals[kc];
    }

    // ---- Issue ALL value gathers first (used last -> max latency overlap),
    //      then all key gathers. 26 float4 in flight per wave. ----
    float4 vr[NITER];
    #pragma unroll
    for (int i = 0; i < NITER; ++i) {
        vr[i] = *reinterpret_cast<const float4*>(
            value_table + (size_t)vidx[i] * DIM + lane * 4);
    }
    float4 kr[NITER];
    #pragma unroll
    for (int i = 0; i < NITER; ++i) {
        kr[i] = *reinterpret_cast<const float4*>(
            key_table + (size_t)kidx[i] * DIM + lane * 4);
    }

    // ---- Phase 1: dots + interleaved butterfly reductions ----
    float dot[NITER];
    #pragma unroll
    for (int i = 0; i < NITER; ++i) {
        dot[i] = q.x * kr[i].x + q.y * kr[i].y + q.z * kr[i].z + q.w * kr[i].w;
    }
    #pragma unroll
    for (int off = 32; off; off >>= 1) {
        #pragma unroll
        for (int i = 0; i < NITER; ++i) dot[i] += __shfl_xor(dot[i], off);
    }
    if (lane == 0) {
        #pragma unroll
        for (int i = 0; i < NITER; ++i) {
            const int k = wave + 4 * i;   // k <= 51 < 64
            s_logit[k] = dot[i];
        }
    }
    __syncthreads();

    // ---- Phase 2: softmax, redundantly per wave ----
    float lg = (lane < len) ? s_logit[lane] : -INFINITY;
    float m = lg;
    #pragma unroll
    for (int off = 32; off; off >>= 1) m = fmaxf(m, __shfl_xor(m, off));
    float e = (lane < len) ? __expf(lg - m) : 0.0f;
    float s = e;
    #pragma unroll
    for (int off = 32; off; off >>= 1) s += __shfl_xor(s, off);
    const float p = e * (1.0f / s);   // p == 0 for lanes >= len

    // ---- Phase 3: weighted sum of the already-in-flight value rows ----
    float4 acc = make_float4(0.f, 0.f, 0.f, 0.f);
    #pragma unroll
    for (int i = 0; i < NITER; ++i) {
        const int k = wave + 4 * i;
        const float w = __shfl(p, (k < 63) ? k : 63);  // lanes >= len hold p=0
        acc.x += w * vr[i].x;
        acc.y += w * vr[i].y;
        acc.z += w * vr[i].z;
        acc.w += w * vr[i].w;
    }
    s_acc[wave][lane] = acc;
    __syncthreads();

    if (wave == 0) {
        float4 a0 = s_acc[0][lane];
        const float4 a1 = s_acc[1][lane];
        const float4 a2 = s_acc[2][lane];
        const float4 a3 = s_acc[3][lane];
        a0.x += a1.x + a2.x + a3.x;
        a0.y += a1.y + a2.y + a3.y;
        a0.z += a1.z + a2.z + a3.z;
        a0.w += a1.w + a2.w + a3.w;
        *reinterpret_cast<float4*>(out + (size_t)b * DIM + lane * 4) = a0;
    }
}

extern "C" void kernel_launch(void* const* d_in, const int* in_sizes, int n_in,
                              void* d_out, int out_size, void* d_ws, size_t ws_size,
                              hipStream_t stream) {
    const int*   keys        = (const int*)d_in[0];
    const int*   values      = (const int*)d_in[1];
    const int*   pair_len    = (const int*)d_in[2];
    const float* query       = (const float*)d_in[3];
    const float* key_table   = (const float*)d_in[4];
    const float* value_table = (const float*)d_in[5];
    float* out = (float*)d_out;

    kv_memory_kernel<<<BATCH, 256, 0, stream>>>(
        keys, values, pair_len, query, key_table, value_table, out);
}